// Round 13
// baseline (15412.291 us; speedup 1.0000x reference)
//
#include <hip/hip_runtime.h>

typedef _Float16 h2f __attribute__((ext_vector_type(2)));

#define LOG2E 1.44269504088896f

__device__ __forceinline__ float fexp2(float x){ return __builtin_amdgcn_exp2f(x); }
__device__ __forceinline__ float frcp (float x){ return __builtin_amdgcn_rcpf(x); }
__device__ __forceinline__ float sigm (float x){ return frcp(1.f + fexp2(-LOG2E*x)); }
__device__ __forceinline__ float tanhf2(float x){
  x = fminf(15.f, fmaxf(-15.f, x));
  float e = fexp2(2.f*LOG2E*x);
  return (e-1.f)*frcp(e+1.f);
}
__device__ __forceinline__ unsigned pkh2(float a, float b){
  h2f h; h.x = (_Float16)a; h.y = (_Float16)b;
  return __builtin_bit_cast(unsigned, h);
}

#if __has_builtin(__builtin_amdgcn_fdot2)
__device__ __forceinline__ float dot2(unsigned a, unsigned b, float c){
  return __builtin_amdgcn_fdot2(__builtin_bit_cast(h2f,a), __builtin_bit_cast(h2f,b), c, false);
}
#else
__device__ __forceinline__ float dot2(unsigned a, unsigned b, float c){
  h2f ha=__builtin_bit_cast(h2f,a), hb=__builtin_bit_cast(h2f,b);
  return c + (float)ha.x*(float)hb.x + (float)ha.y*(float)hb.y;
}
#endif

__device__ __forceinline__ void dot8_2(uint4 w, uint4 x, float& a0, float& a1){
  a0 = dot2(w.x, x.x, a0); a1 = dot2(w.y, x.y, a1);
  a0 = dot2(w.z, x.z, a0); a1 = dot2(w.w, x.w, a1);
}

// simple matvec (prep kernels)
template<int N, int K8>
__device__ __forceinline__ float mv(const uint4* __restrict__ W, const uint4* __restrict__ xs, int n){
  float a0 = 0.f, a1 = 0.f;
  #pragma unroll 4
  for (int k8 = 0; k8 < K8; ++k8)
    dot8_2(W[k8*N + n], xs[k8], a0, a1);
  return a0 + a1;
}

// chunked load-then-compute (call-local, fits 64 VGPR, no spills). C | K8.
template<int N, int K8, int C>
__device__ __forceinline__ float mvc(const uint4* __restrict__ W, const uint4* __restrict__ xs, int n){
  float a0 = 0.f, a1 = 0.f;
  #pragma unroll 1
  for (int k8 = 0; k8 < K8; k8 += C){
    uint4 w[C];
    #pragma unroll
    for (int i = 0; i < C; ++i) w[i] = W[(size_t)(k8+i)*N + n];
    #pragma unroll
    for (int i = 0; i < C; ++i) dot8_2(w[i], xs[k8+i], a0, a1);
  }
  return a0 + a1;
}

// agent-scope (device) atomics for cross-WG exchange
__device__ __forceinline__ void axs(unsigned* p, unsigned v){
  __hip_atomic_store(p, v, __ATOMIC_RELAXED, __HIP_MEMORY_SCOPE_AGENT);
}
__device__ __forceinline__ unsigned axl(const unsigned* p){
  return __hip_atomic_load(p, __ATOMIC_RELAXED, __HIP_MEMORY_SCOPE_AGENT);
}
__device__ __forceinline__ unsigned f2u(float f){ return __builtin_bit_cast(unsigned, f); }
__device__ __forceinline__ float u2f(unsigned u){ return __builtin_bit_cast(float, u); }

// local gate-row r (0..383) -> global weight row, half HB = H*128
__device__ __forceinline__ int grow3(int r, int HB){ return (r>>7)*256 + HB + (r & 127); }

// ---------------- workspace layout (bytes) ----------------
static constexpr size_t OFF_W1   = 0;          // 256x400
static constexpr size_t OFF_W2   = 204800;     // 128x256
static constexpr size_t OFF_WIHA = 270336;     // 768x384
static constexpr size_t OFF_WHHA = 860160;     // 768x256
static constexpr size_t OFF_WQ   = 1253376;    // 256x256
static constexpr size_t OFF_WP   = 1384448;    // 256x512
static constexpr size_t OFF_WD1I = 1646592;    // 768x256
static constexpr size_t OFF_WD1H = 2039808;
static constexpr size_t OFF_WD2I = 2433024;
static constexpr size_t OFF_WD2H = 2826240;
static constexpr size_t OFF_WMEL = 3219456;    // 400x256
static constexpr size_t OFF_WM   = 3424256;    // 256x256
static constexpr size_t OFF_TPM  = 3555328;    // tanh(pm) GATHERED uint4[b][g=32][t=512]
static constexpr size_t OFF_ENCH = 37109760;   // enc f16 [b][t][d2]
static constexpr size_t OFF_XCH  = 70664192;   // pair-exchange: 128 pairs x 8KB
// XCH per-pair u32 layout: flg[2][8] @0; xh[2][64] @16; xtq[2][128] @144;
// xe[2][260] @400; xctx[2][64] @920; xdi[2][64] @1048; xh1di[2][128] @1176;
// xh2[2][64] @1432;  (total 1560 u32, block = 2048 u32)

// ---------------- prep kernels ----------------
__global__ void pack_w(const float* __restrict__ src, uint4* __restrict__ dst, int N, int K8){
  int idx = blockIdx.x*blockDim.x + threadIdx.x;
  if (idx >= N*K8) return;
  int n = idx % N, k8 = idx / N;
  const float* s = src + (size_t)n*(K8*8) + k8*8;
  dst[idx] = make_uint4(pkh2(s[0],s[1]), pkh2(s[2],s[3]), pkh2(s[4],s[5]), pkh2(s[6],s[7]));
}

__global__ void conv_enc(const float* __restrict__ enc, unsigned* __restrict__ encH){
  size_t i = blockIdx.x*(size_t)blockDim.x + threadIdx.x;
  if (i >= (size_t)128*512*128) return;
  const float2 f = *(const float2*)(enc + 2*i);
  encH[i] = pkh2(f.x, f.y);
}

// tpm gathered: u32 index = ((b*32 + g)*512 + t)*4 + j ; g = d>>3, j = (d>>1)&3
__global__ __launch_bounds__(1024) void pm_kernel(const float* __restrict__ enc,
    const uint4* __restrict__ Wmp, unsigned* __restrict__ tpm)
{
  int b = blockIdx.y, tc = blockIdx.x;
  int tid = threadIdx.x;
  __shared__ __align__(16) unsigned s_e[4][128];
  if (tid < 512){
    int r = tid >> 7, d2 = tid & 127;
    const float2 f = *(const float2*)(enc + ((size_t)b*512 + tc*4 + r)*256 + 2*d2);
    s_e[r][d2] = pkh2(f.x, f.y);
  }
  __syncthreads();
  int d = tid & 255, r = tid >> 8;
  float acc = mv<256,32>(Wmp, (const uint4*)s_e[r], d);
  float tq = tanhf2(acc);
  float hi = __shfl_down(tq, 1);
  if ((d & 1) == 0){
    int t = tc*4 + r;
    tpm[ (((size_t)b*32 + (d>>3))*512 + t)*4 + ((d>>1)&3) ] = pkh2(tq, hi);
  }
}

// Prenet hoisted: pre2 stashed in first 64 u32 of out_align[b][t].
__global__ __launch_bounds__(256) void prenet_kernel(
    const float* __restrict__ inputs,
    const float* __restrict__ b1, const float* __restrict__ b2,
    const uint4* __restrict__ W1p, const uint4* __restrict__ W2p,
    float* __restrict__ out)
{
  int t = blockIdx.x, b = blockIdx.y;
  int tid = threadIdx.x;
  __shared__ __align__(16) unsigned s_x[200];
  __shared__ __align__(16) unsigned s_p1[128];
  __shared__ float s_a[256];
  if (tid < 200){
    unsigned xv = 0u;
    if (t > 0){
      const float2 f = *(const float2*)(inputs + (size_t)b*80000 + (size_t)(t-1)*400 + 2*tid);
      xv = pkh2(f.x, f.y);
    }
    s_x[tid] = xv;
  }
  __syncthreads();
  float a = fmaxf(mv<256,50>(W1p, (const uint4*)s_x, tid) + b1[tid], 0.f);
  s_a[tid] = a;
  __syncthreads();
  if (tid < 128) s_p1[tid] = pkh2(s_a[2*tid], s_a[2*tid+1]);
  __syncthreads();
  if (tid < 128){
    float p = fmaxf(mv<128,32>(W2p, (const uint4*)s_p1, tid) + b2[tid], 0.f);
    float pN = __shfl_down(p, 1);
    if (!(tid & 1)){
      unsigned* dst = (unsigned*)(out + (size_t)10240000 + ((size_t)b*200 + t)*512);
      dst[tid>>1] = pkh2(p, pN);
    }
  }
}

// Mel hoisted: decoder left packed dec_in at out_mel[b][t][0:128] u32.
__global__ __launch_bounds__(512) void mel_kernel(
    const float* __restrict__ bmel, const uint4* __restrict__ Wmelp,
    float* __restrict__ out)
{
  int t = blockIdx.x, b = blockIdx.y;
  int tid = threadIdx.x;
  __shared__ __align__(16) unsigned s_d[128];
  float* po = out + ((size_t)b*200 + t)*400;
  if (tid < 128) s_d[tid] = ((const unsigned*)po)[tid];
  __syncthreads();
  if (tid < 400){
    float r = mvc<400,32,8>(Wmelp, (const uint4*)s_d, tid) + bmel[tid];
    __builtin_nontemporal_store(r, &po[tid]);
  }
}

// ---------------- decoder: pair row-split (256 WGs, pair = (b, b+128)) ----
// Each WG computes HALF the rows of every matvec -> per-WG stream ~1.7MB/step
// (vs 3.5 in R11). Full hidden state rebuilt via 7 small agent-scope atomic
// exchanges/step. Co-residency: 256 WGs x 16 waves = 4096 <= 8192 device
// waves, 64 VGPR, ~31KB LDS -> all resident; spin-wait cannot deadlock.
// Flags zeroed by hipMemsetAsync each launch; flag value = t+1 (monotone).
__global__ __launch_bounds__(1024, 1) void decoder(
   const float* __restrict__ biha, const float* __restrict__ bhha,
   const float* __restrict__ vvec, const float* __restrict__ bp,
   const float* __restrict__ bd1i, const float* __restrict__ bd1h,
   const float* __restrict__ bd2i, const float* __restrict__ bd2h,
   const uint4* __restrict__ Wihap, const uint4* __restrict__ Whhap,
   const uint4* __restrict__ Wqp, const uint4* __restrict__ Wpp,
   const uint4* __restrict__ Wd1ip, const uint4* __restrict__ Wd1hp,
   const uint4* __restrict__ Wd2ip, const uint4* __restrict__ Wd2hp,
   const unsigned* __restrict__ tpm, const unsigned* __restrict__ encH,
   unsigned* __restrict__ xch_all, float* __restrict__ out)
{
  const int tid = threadIdx.x;
  const int b  = blockIdx.x & 127;
  const int H  = blockIdx.x >> 7;        // row-half this WG owns
  const int HB = H*128;                  // gate-row base
  const int PH = 1 - H;

  unsigned* xch = xch_all + (size_t)b*2048;
  unsigned* myflg = xch + H*8;
  unsigned* paflg = xch + PH*8;
  unsigned* xh_my   = xch + 16  + H*64;   unsigned* xh_pa   = xch + 16  + PH*64;
  unsigned* xtq_my  = xch + 144 + H*128;  unsigned* xtq_pa  = xch + 144 + PH*128;
  unsigned* xe_my   = xch + 400 + H*260;  unsigned* xe_pa   = xch + 400 + PH*260;
  unsigned* xctx_my = xch + 920 + H*64;   unsigned* xctx_pa = xch + 920 + PH*64;
  unsigned* xdi_my  = xch + 1048 + H*64;  unsigned* xdi_pa  = xch + 1048 + PH*64;
  unsigned* xh1_my  = xch + 1176 + H*128; unsigned* xh1_pa  = xch + 1176 + PH*128;
  unsigned* xh2_my  = xch + 1432 + H*64;  unsigned* xh2_pa  = xch + 1432 + PH*64;

  __shared__ __align__(16) unsigned s_cin2[192]; // [pre2(64) | ctx(128)] full
  __shared__ __align__(16) unsigned s_cat2[256]; // [attn_h(128) | ctx(128)] full
  __shared__ __align__(16) unsigned s_di2[128];  // full
  __shared__ __align__(16) unsigned s_h12[128];  // full
  __shared__ __align__(16) unsigned s_h22[128];  // full
  __shared__ float  s_gha[384], s_gh1[384], s_gh2[384];  // own-half rows
  __shared__ float  s_p2[2][384];                        // split-K partials
  __shared__ float  s_ahf[128], s_h1f[128], s_h2f[128];  // own-half f32 state
  __shared__ float  s_dif[128];
  __shared__ float4 s_tv[128];     // full {tq,tq,v,v}
  __shared__ float  s_lp[4][256];
  __shared__ float2 s_cp[16][64];
  __shared__ float  s_mvp[4][128];
  __shared__ float  s_align[512];
  __shared__ float  s_red[4];

  if (tid < 192) s_cin2[tid] = 0u;
  if (tid < 256) s_cat2[tid] = 0u;
  if (tid < 128){ s_di2[tid]=0u; s_h12[tid]=0u; s_h22[tid]=0u;
                  s_ahf[tid]=0.f; s_h1f[tid]=0.f; s_h2f[tid]=0.f;
                  s_tv[tid].z = vvec[2*tid]; s_tv[tid].w = vvec[2*tid+1]; }
  __syncthreads();

  const unsigned* encB = encH + (size_t)b*65536;
  const uint4*    tpm4 = (const uint4*)tpm + (size_t)b*16384;
  float* outMel = out + (size_t)b*80000;
  float* outAl  = out + 10240000ull + (size_t)b*102400;

  const uint4* cin4 = (const uint4*)s_cin2;
  const uint4* cat4 = (const uint4*)s_cat2;
  const uint4* di4  = (const uint4*)s_di2;
  const uint4* h14  = (const uint4*)s_h12;
  const uint4* h24  = (const uint4*)s_h22;

  for (int t = 0; t < 200; ++t){
    const unsigned seq = (unsigned)(t + 1);
    // ===== P1: gha half [0,384) || gh1 half [384,768) || gh2 rows 0..191 || pre2
    if (tid < 384){
      int g = grow3(tid, HB);
      s_gha[tid] = mvc<768,32,8>(Whhap, cat4, g) + bhha[g];
    } else if (tid < 768){
      int r = tid - 384, g = grow3(r, HB);
      s_gh1[r] = mvc<768,32,8>(Wd1hp, h14, g) + bd1h[g];
    } else if (tid < 960){
      int r = tid - 768, g = grow3(r, HB);
      s_gh2[r] = mvc<768,32,8>(Wd2hp, h24, g) + bd2h[g];
    } else {
      s_cin2[tid-960] = ((const unsigned*)(outAl + (size_t)t*512))[tid-960];
    }
    __syncthreads();
    // ===== P2: gi_a half split-K2 (768) || gh2 rows 192..383 (192)
    if (tid < 768){
      int p = tid/384, r = tid - p*384, g = grow3(r, HB);
      s_p2[p][r] = mvc<768,24,8>(Wihap + (size_t)(p*24)*768, cin4 + p*24, g);
    } else if (tid < 960){
      int r = 192 + tid - 768, g = grow3(r, HB);
      s_gh2[r] = mvc<768,32,8>(Wd2hp, h24, g) + bd2h[r == r ? g : g];
    }
    __syncthreads();
    // ===== GA: attn-GRU gates own half (128) -> E1
    if (tid < 128){
      int j = tid;
      float gr = s_p2[0][j]     + s_p2[1][j]     + biha[HB+j]       + s_gha[j];
      float gz = s_p2[0][128+j] + s_p2[1][128+j] + biha[256+HB+j]   + s_gha[128+j];
      float gn = s_p2[0][256+j] + s_p2[1][256+j] + biha[512+HB+j];
      float rr = sigm(gr), z = sigm(gz);
      float nv = tanhf2(gn + rr*s_gha[256+j]);
      float h  = nv + z*(s_ahf[j] - nv);
      s_ahf[j] = h;
      float hN = __shfl_down(h, 1);
      if (!(j&1)){
        unsigned pk = pkh2(h, hN);
        s_cat2[H*64 + (j>>1)] = pk;
        axs(xh_my + (j>>1), pk);
      }
    }
    __syncthreads();
    if (tid == 0) __hip_atomic_store(myflg+0, seq, __ATOMIC_RELEASE, __HIP_MEMORY_SCOPE_AGENT);
    if (tid == 0){ while (__hip_atomic_load(paflg+0, __ATOMIC_ACQUIRE, __HIP_MEMORY_SCOPE_AGENT) < seq) __builtin_amdgcn_s_sleep(1); }
    __syncthreads();
    if (tid < 64) s_cat2[PH*64 + tid] = axl(xh_pa + tid);
    __syncthreads();
    // ===== P4: q own rows split-K4 (512)
    if (tid < 512){
      int r = tid & 127, p = tid >> 7;
      s_mvp[p][r] = mvc<256,8,8>(Wqp + (size_t)(p*8)*256, cat4 + p*8, HB + r);
    }
    __syncthreads();
    // ===== QT + E2
    if (tid < 128){
      float q = s_mvp[0][tid]+s_mvp[1][tid]+s_mvp[2][tid]+s_mvp[3][tid];
      float tq = tanhf2(q);
      int d = HB + tid;
      ((float*)&s_tv[d>>1])[d&1] = tq;
      axs(xtq_my + tid, f2u(tq));
    }
    __syncthreads();
    if (tid == 0) __hip_atomic_store(myflg+1, seq, __ATOMIC_RELEASE, __HIP_MEMORY_SCOPE_AGENT);
    if (tid == 0){ while (__hip_atomic_load(paflg+1, __ATOMIC_ACQUIRE, __HIP_MEMORY_SCOPE_AGENT) < seq) __builtin_amdgcn_s_sleep(1); }
    __syncthreads();
    if (tid < 128){
      int d = PH*128 + tid;
      ((float*)&s_tv[d>>1])[d&1] = u2f(axl(xtq_pa + tid));
    }
    __syncthreads();
    // ===== P5: logits own t'-half (1024 = 256 tt' x 4 dh)
    {
      int ttL = tid & 255, dh = tid >> 8;
      const uint4* tp = tpm4 + (H*256 + ttL);
      float acc = 0.f;
      {
        uint4 T[8];
        #pragma unroll
        for (int i = 0; i < 8; ++i) T[i] = tp[(size_t)(dh*8+i)*512];
        #pragma unroll
        for (int i = 0; i < 8; ++i){
          #pragma unroll
          for (int j = 0; j < 4; ++j){
            unsigned u = ((const unsigned*)&T[i])[j];
            h2f ta = __builtin_bit_cast(h2f, u);
            float4 tv = s_tv[(dh*8+i)*4 + j];
            float ta0 = (float)ta.x, ta1 = (float)ta.y;
            float n0 = ta0 + tv.x, n1 = ta1 + tv.y;
            float d0 = fmaf(ta0, tv.x, 1.f), d1 = fmaf(ta1, tv.y, 1.f);
            float rcp = frcp(d0*d1);
            acc = fmaf(fmaf(tv.w*n1, d0, (tv.z*n0)*d1), rcp, acc);
          }
        }
      }
      s_lp[dh][ttL] = acc;
    }
    __syncthreads();
    // ===== SM: exp + own partial sum -> E3 -> full align
    float e_own = 0.f, S_own = 0.f;
    if (tid < 256){
      float lg = s_lp[0][tid]+s_lp[1][tid]+s_lp[2][tid]+s_lp[3][tid];
      e_own = fexp2(LOG2E*lg);
      float s = e_own;
      #pragma unroll
      for (int off = 32; off >= 1; off >>= 1) s += __shfl_xor(s, off);
      if ((tid & 63) == 0) s_red[tid>>6] = s;
    }
    __syncthreads();
    if (tid < 256){
      S_own = (s_red[0]+s_red[1])+(s_red[2]+s_red[3]);
      axs(xe_my + tid, f2u(e_own));
      if (tid == 0) axs(xe_my + 256, f2u(S_own));
    }
    __syncthreads();
    if (tid == 0) __hip_atomic_store(myflg+2, seq, __ATOMIC_RELEASE, __HIP_MEMORY_SCOPE_AGENT);
    if (tid == 0){ while (__hip_atomic_load(paflg+2, __ATOMIC_ACQUIRE, __HIP_MEMORY_SCOPE_AGENT) < seq) __builtin_amdgcn_s_sleep(1); }
    __syncthreads();
    if (tid < 256){
      float e_p = u2f(axl(xe_pa + tid));
      float S = S_own + u2f(axl(xe_pa + 256));
      float rS = frcp(S);
      float a_own = e_own * rS;
      s_align[H*256 + tid]  = a_own;
      s_align[PH*256 + tid] = e_p * rS;
      __builtin_nontemporal_store(a_own, &outAl[(size_t)t*512 + H*256 + tid]);
    }
    __syncthreads();
    // ===== P6: ctx own d-half (1024 = 64 d2L x 16 tc)
    {
      int d2L = tid & 63, tc = tid >> 6;
      int d2 = H*64 + d2L;
      const unsigned* eb = encB + d2;
      float ax = 0.f, ay = 0.f;
      #pragma unroll 1
      for (int c = 0; c < 32; c += 8){
        unsigned ew[8];
        #pragma unroll
        for (int i = 0; i < 8; ++i) ew[i] = eb[(size_t)(tc*32 + c + i)*128];
        #pragma unroll
        for (int i = 0; i < 8; ++i){
          float a = s_align[tc*32 + c + i];
          h2f e2 = __builtin_bit_cast(h2f, ew[i]);
          ax += a*(float)e2.x; ay += a*(float)e2.y;
        }
      }
      s_cp[tc][d2L] = make_float2(ax, ay);
    }
    __syncthreads();
    // ===== CR: ctx reduce own half (128) -> E4
    if (tid < 128){
      int d2L = tid >> 1, comp = tid & 1;
      const float* base = (const float*)s_cp + d2L*2 + comp;
      float c = 0.f;
      #pragma unroll
      for (int tc = 0; tc < 16; ++tc) c += base[(size_t)tc*128];
      float cN = __shfl_down(c, 1);
      if (!(tid&1)){
        unsigned pk = pkh2(c, cN);
        int u = H*64 + (tid>>1);
        s_cat2[128 + u] = pk; s_cin2[64 + u] = pk;
        axs(xctx_my + (tid>>1), pk);
      }
    }
    __syncthreads();
    if (tid == 0) __hip_atomic_store(myflg+3, seq, __ATOMIC_RELEASE, __HIP_MEMORY_SCOPE_AGENT);
    if (tid == 0){ while (__hip_atomic_load(paflg+3, __ATOMIC_ACQUIRE, __HIP_MEMORY_SCOPE_AGENT) < seq) __builtin_amdgcn_s_sleep(1); }
    __syncthreads();
    if (tid < 64){
      unsigned pk = axl(xctx_pa + tid);
      s_cat2[128 + PH*64 + tid] = pk; s_cin2[64 + PH*64 + tid] = pk;
    }
    __syncthreads();
    // ===== P7: dec_in own rows split-K4 (512, K=512)
    if (tid < 512){
      int r = tid & 127, p = tid >> 7;
      s_mvp[p][r] = mvc<256,16,8>(Wpp + (size_t)(p*16)*256, cat4 + p*16, HB + r);
    }
    __syncthreads();
    // ===== DM -> E5
    if (tid < 128){
      float di = s_mvp[0][tid]+s_mvp[1][tid]+s_mvp[2][tid]+s_mvp[3][tid] + bp[HB+tid];
      s_dif[tid] = di;
      float dN = __shfl_down(di, 1);
      if (!(tid&1)){
        unsigned pk = pkh2(di, dN);
        s_di2[H*64 + (tid>>1)] = pk;
        axs(xdi_my + (tid>>1), pk);
      }
    }
    __syncthreads();
    if (tid == 0) __hip_atomic_store(myflg+4, seq, __ATOMIC_RELEASE, __HIP_MEMORY_SCOPE_AGENT);
    if (tid == 0){ while (__hip_atomic_load(paflg+4, __ATOMIC_ACQUIRE, __HIP_MEMORY_SCOPE_AGENT) < seq) __builtin_amdgcn_s_sleep(1); }
    __syncthreads();
    if (tid < 64) s_di2[PH*64 + tid] = axl(xdi_pa + tid);
    __syncthreads();
    // ===== P8: gi_d1 own half split-K2 (768)
    if (tid < 768){
      int p = tid/384, r = tid - p*384, g = grow3(r, HB);
      s_p2[p][r] = mvc<768,16,8>(Wd1ip + (size_t)(p*16)*768, di4 + p*16, g);
    }
    __syncthreads();
    // ===== G1 -> E6 (h1 half + updated di half)
    if (tid < 128){
      int j = tid;
      float gr = s_p2[0][j]     + s_p2[1][j]     + bd1i[HB+j]     + s_gh1[j];
      float gz = s_p2[0][128+j] + s_p2[1][128+j] + bd1i[256+HB+j] + s_gh1[128+j];
      float gn = s_p2[0][256+j] + s_p2[1][256+j] + bd1i[512+HB+j];
      float rr = sigm(gr), z = sigm(gz);
      float nv = tanhf2(gn + rr*s_gh1[256+j]);
      float h  = nv + z*(s_h1f[j] - nv);
      s_h1f[j] = h;
      float di = s_dif[j] + h; s_dif[j] = di;
      float hN = __shfl_down(h, 1), dN = __shfl_down(di, 1);
      if (!(j&1)){
        unsigned hp = pkh2(h, hN), dp = pkh2(di, dN);
        s_h12[H*64 + (j>>1)] = hp; s_di2[H*64 + (j>>1)] = dp;
        axs(xh1_my + (j>>1), hp); axs(xh1_my + 64 + (j>>1), dp);
      }
    }
    __syncthreads();
    if (tid == 0) __hip_atomic_store(myflg+5, seq, __ATOMIC_RELEASE, __HIP_MEMORY_SCOPE_AGENT);
    if (tid == 0){ while (__hip_atomic_load(paflg+5, __ATOMIC_ACQUIRE, __HIP_MEMORY_SCOPE_AGENT) < seq) __builtin_amdgcn_s_sleep(1); }
    __syncthreads();
    if (tid < 64){
      s_h12[PH*64 + tid] = axl(xh1_pa + tid);
      s_di2[PH*64 + tid] = axl(xh1_pa + 64 + tid);
    }
    __syncthreads();
    // ===== P9: gi_d2 own half split-K2 (768)
    if (tid < 768){
      int p = tid/384, r = tid - p*384, g = grow3(r, HB);
      s_p2[p][r] = mvc<768,16,8>(Wd2ip + (size_t)(p*16)*768, di4 + p*16, g);
    }
    __syncthreads();
    // ===== G2 -> E7 (h2 half) + own mel-half stash
    if (tid < 128){
      int j = tid;
      float gr = s_p2[0][j]     + s_p2[1][j]     + bd2i[HB+j]     + s_gh2[j];
      float gz = s_p2[0][128+j] + s_p2[1][128+j] + bd2i[256+HB+j] + s_gh2[128+j];
      float gn = s_p2[0][256+j] + s_p2[1][256+j] + bd2i[512+HB+j];
      float rr = sigm(gr), z = sigm(gz);
      float nv = tanhf2(gn + rr*s_gh2[256+j]);
      float h  = nv + z*(s_h2f[j] - nv);
      s_h2f[j] = h;
      float di = s_dif[j] + h;
      float hN = __shfl_down(h, 1), dN = __shfl_down(di, 1);
      if (!(j&1)){
        unsigned hp = pkh2(h, hN);
        s_h22[H*64 + (j>>1)] = hp;
        axs(xh2_my + (j>>1), hp);
        ((unsigned*)(outMel + (size_t)t*400))[H*64 + (j>>1)] = pkh2(di, dN);
      }
    }
    __syncthreads();
    if (tid == 0) __hip_atomic_store(myflg+6, seq, __ATOMIC_RELEASE, __HIP_MEMORY_SCOPE_AGENT);
    if (tid == 0){ while (__hip_atomic_load(paflg+6, __ATOMIC_ACQUIRE, __HIP_MEMORY_SCOPE_AGENT) < seq) __builtin_amdgcn_s_sleep(1); }
    __syncthreads();
    if (tid < 64) s_h22[PH*64 + tid] = axl(xh2_pa + tid);
    __syncthreads();
  }
}

// ---------------- launch ----------------
extern "C" void kernel_launch(void* const* d_in, const int* in_sizes, int n_in,
                              void* d_out, int out_size, void* d_ws, size_t ws_size,
                              hipStream_t stream){
  (void)in_sizes; (void)n_in; (void)out_size; (void)ws_size;
  const float* enc    = (const float*)d_in[0];
  const float* inputs = (const float*)d_in[1];
  const float* W1 = (const float*)d_in[2];   const float* b1 = (const float*)d_in[3];
  const float* W2 = (const float*)d_in[4];   const float* b2 = (const float*)d_in[5];
  const float* Wiha = (const float*)d_in[6]; const float* Whha = (const float*)d_in[7];
  const float* biha = (const float*)d_in[8]; const float* bhha = (const float*)d_in[9];
  const float* Wq = (const float*)d_in[10];  const float* v  = (const float*)d_in[11];
  const float* Wm = (const float*)d_in[12];
  const float* Wp = (const float*)d_in[13];  const float* bp = (const float*)d_in[14];
  const float* Wd1i = (const float*)d_in[15]; const float* Wd1h = (const float*)d_in[16];
  const float* bd1i = (const float*)d_in[17]; const float* bd1h = (const float*)d_in[18];
  const float* Wd2i = (const float*)d_in[19]; const float* Wd2h = (const float*)d_in[20];
  const float* bd2i = (const float*)d_in[21]; const float* bd2h = (const float*)d_in[22];
  const float* Wmel = (const float*)d_in[23]; const float* bmel = (const float*)d_in[24];

  char* ws = (char*)d_ws;
  uint4* W1p   = (uint4*)(ws + OFF_W1);
  uint4* W2p   = (uint4*)(ws + OFF_W2);
  uint4* Wihap = (uint4*)(ws + OFF_WIHA);
  uint4* Whhap = (uint4*)(ws + OFF_WHHA);
  uint4* Wqp   = (uint4*)(ws + OFF_WQ);
  uint4* Wpp   = (uint4*)(ws + OFF_WP);
  uint4* Wd1ip = (uint4*)(ws + OFF_WD1I);
  uint4* Wd1hp = (uint4*)(ws + OFF_WD1H);
  uint4* Wd2ip = (uint4*)(ws + OFF_WD2I);
  uint4* Wd2hp = (uint4*)(ws + OFF_WD2H);
  uint4* Wmelp = (uint4*)(ws + OFF_WMEL);
  uint4* Wmp   = (uint4*)(ws + OFF_WM);
  unsigned* tpm  = (unsigned*)(ws + OFF_TPM);
  unsigned* encH = (unsigned*)(ws + OFF_ENCH);
  unsigned* xch  = (unsigned*)(ws + OFF_XCH);

  auto P = [&](const float* s, uint4* dst, int N, int K){
    int k8 = K/8, tot = N*k8;
    pack_w<<<(tot+255)/256, 256, 0, stream>>>(s, dst, N, k8);
  };
  P(W1, W1p, 256, 400);   P(W2, W2p, 128, 256);
  P(Wiha, Wihap, 768, 384); P(Whha, Whhap, 768, 256);
  P(Wq, Wqp, 256, 256);   P(Wm, Wmp, 256, 256);
  P(Wp, Wpp, 256, 512);
  P(Wd1i, Wd1ip, 768, 256); P(Wd1h, Wd1hp, 768, 256);
  P(Wd2i, Wd2ip, 768, 256); P(Wd2h, Wd2hp, 768, 256);
  P(Wmel, Wmelp, 400, 256);

  // zero the exchange flags+buffers every launch (deterministic, capture-safe)
  hipMemsetAsync(xch, 0, 128*2048*sizeof(unsigned), stream);

  conv_enc<<<32768, 256, 0, stream>>>(enc, encH);
  pm_kernel<<<dim3(128,128), 1024, 0, stream>>>(enc, Wmp, tpm);
  prenet_kernel<<<dim3(200,128), 256, 0, stream>>>(inputs, b1, b2, W1p, W2p, (float*)d_out);

  decoder<<<256, 1024, 0, stream>>>(
      biha, bhha, v, bp, bd1i, bd1h, bd2i, bd2h,
      Wihap, Whhap, Wqp, Wpp, Wd1ip, Wd1hp, Wd2ip, Wd2hp,
      tpm, encH, xch, (float*)d_out);

  mel_kernel<<<dim3(200,128), 512, 0, stream>>>(bmel, Wmelp, (float*)d_out);
}

// Round 15
// 10852.183 us; speedup vs baseline: 1.4202x; 1.4202x over previous
//
#include <hip/hip_runtime.h>

typedef _Float16 h2f __attribute__((ext_vector_type(2)));

#define LOG2E 1.44269504088896f

__device__ __forceinline__ float fexp2(float x){ return __builtin_amdgcn_exp2f(x); }
__device__ __forceinline__ float frcp (float x){ return __builtin_amdgcn_rcpf(x); }
__device__ __forceinline__ float sigm (float x){ return frcp(1.f + fexp2(-LOG2E*x)); }
__device__ __forceinline__ float tanhf2(float x){
  x = fminf(15.f, fmaxf(-15.f, x));
  float e = fexp2(2.f*LOG2E*x);
  return (e-1.f)*frcp(e+1.f);
}
__device__ __forceinline__ unsigned pkh2(float a, float b){
  h2f h; h.x = (_Float16)a; h.y = (_Float16)b;
  return __builtin_bit_cast(unsigned, h);
}

#if __has_builtin(__builtin_amdgcn_fdot2)
__device__ __forceinline__ float dot2(unsigned a, unsigned b, float c){
  return __builtin_amdgcn_fdot2(__builtin_bit_cast(h2f,a), __builtin_bit_cast(h2f,b), c, false);
}
#else
__device__ __forceinline__ float dot2(unsigned a, unsigned b, float c){
  h2f ha=__builtin_bit_cast(h2f,a), hb=__builtin_bit_cast(h2f,b);
  return c + (float)ha.x*(float)hb.x + (float)ha.y*(float)hb.y;
}
#endif

__device__ __forceinline__ void dot8_2(uint4 w, uint4 x, float& a0, float& a1){
  a0 = dot2(w.x, x.x, a0); a1 = dot2(w.y, x.y, a1);
  a0 = dot2(w.z, x.z, a0); a1 = dot2(w.w, x.w, a1);
}

// simple matvec (prep kernels)
template<int N, int K8>
__device__ __forceinline__ float mv(const uint4* __restrict__ W, const uint4* __restrict__ xs, int n){
  float a0 = 0.f, a1 = 0.f;
  #pragma unroll 4
  for (int k8 = 0; k8 < K8; ++k8)
    dot8_2(W[k8*N + n], xs[k8], a0, a1);
  return a0 + a1;
}

// chunked load-then-compute (call-local, fits 64 VGPR, no spills). C | K8.
template<int N, int K8, int C>
__device__ __forceinline__ float mvc(const uint4* __restrict__ W, const uint4* __restrict__ xs, int n){
  float a0 = 0.f, a1 = 0.f;
  #pragma unroll 1
  for (int k8 = 0; k8 < K8; k8 += C){
    uint4 w[C];
    #pragma unroll
    for (int i = 0; i < C; ++i) w[i] = W[(size_t)(k8+i)*N + n];
    #pragma unroll
    for (int i = 0; i < C; ++i) dot8_2(w[i], xs[k8+i], a0, a1);
  }
  return a0 + a1;
}

// ---------------- workspace layout (bytes) ----------------
static constexpr size_t OFF_W1   = 0;          // 256x400
static constexpr size_t OFF_W2   = 204800;     // 128x256
static constexpr size_t OFF_WIHA = 270336;     // 768x384
static constexpr size_t OFF_WHHA = 860160;     // 768x256
static constexpr size_t OFF_WQ   = 1253376;    // 256x256
static constexpr size_t OFF_WP   = 1384448;    // 256x512
static constexpr size_t OFF_WD1I = 1646592;    // 768x256
static constexpr size_t OFF_WD1H = 2039808;
static constexpr size_t OFF_WD2I = 2433024;
static constexpr size_t OFF_WD2H = 2826240;
static constexpr size_t OFF_WMEL = 3219456;    // 400x256
static constexpr size_t OFF_WM   = 3424256;    // 256x256
static constexpr size_t OFF_TPM  = 3555328;    // tanh(pm) GATHERED uint4[b][g=32][t=512]
static constexpr size_t OFF_ENCH = 37109760;   // enc f16 [b][t][d2]

// ---------------- prep kernels ----------------
__global__ void pack_w(const float* __restrict__ src, uint4* __restrict__ dst, int N, int K8){
  int idx = blockIdx.x*blockDim.x + threadIdx.x;
  if (idx >= N*K8) return;
  int n = idx % N, k8 = idx / N;
  const float* s = src + (size_t)n*(K8*8) + k8*8;
  dst[idx] = make_uint4(pkh2(s[0],s[1]), pkh2(s[2],s[3]), pkh2(s[4],s[5]), pkh2(s[6],s[7]));
}

__global__ void conv_enc(const float* __restrict__ enc, unsigned* __restrict__ encH){
  size_t i = blockIdx.x*(size_t)blockDim.x + threadIdx.x;
  if (i >= (size_t)128*512*128) return;
  const float2 f = *(const float2*)(enc + 2*i);
  encH[i] = pkh2(f.x, f.y);
}

// tpm gathered: u32 index = ((b*32 + g)*512 + t)*4 + j ; g = d>>3, j = (d>>1)&3
__global__ __launch_bounds__(1024) void pm_kernel(const float* __restrict__ enc,
    const uint4* __restrict__ Wmp, unsigned* __restrict__ tpm)
{
  int b = blockIdx.y, tc = blockIdx.x;
  int tid = threadIdx.x;
  __shared__ __align__(16) unsigned s_e[4][128];
  if (tid < 512){
    int r = tid >> 7, d2 = tid & 127;
    const float2 f = *(const float2*)(enc + ((size_t)b*512 + tc*4 + r)*256 + 2*d2);
    s_e[r][d2] = pkh2(f.x, f.y);
  }
  __syncthreads();
  int d = tid & 255, r = tid >> 8;
  float acc = mv<256,32>(Wmp, (const uint4*)s_e[r], d);
  float tq = tanhf2(acc);
  float hi = __shfl_down(tq, 1);
  if ((d & 1) == 0){
    int t = tc*4 + r;
    tpm[ (((size_t)b*32 + (d>>3))*512 + t)*4 + ((d>>1)&3) ] = pkh2(tq, hi);
  }
}

// Prenet hoisted: pre2 stashed in first 64 u32 of out_align[b][t].
__global__ __launch_bounds__(256) void prenet_kernel(
    const float* __restrict__ inputs,
    const float* __restrict__ b1, const float* __restrict__ b2,
    const uint4* __restrict__ W1p, const uint4* __restrict__ W2p,
    float* __restrict__ out)
{
  int t = blockIdx.x, b = blockIdx.y;
  int tid = threadIdx.x;
  __shared__ __align__(16) unsigned s_x[200];
  __shared__ __align__(16) unsigned s_p1[128];
  __shared__ float s_a[256];
  if (tid < 200){
    unsigned xv = 0u;
    if (t > 0){
      const float2 f = *(const float2*)(inputs + (size_t)b*80000 + (size_t)(t-1)*400 + 2*tid);
      xv = pkh2(f.x, f.y);
    }
    s_x[tid] = xv;
  }
  __syncthreads();
  float a = fmaxf(mv<256,50>(W1p, (const uint4*)s_x, tid) + b1[tid], 0.f);
  s_a[tid] = a;
  __syncthreads();
  if (tid < 128) s_p1[tid] = pkh2(s_a[2*tid], s_a[2*tid+1]);
  __syncthreads();
  if (tid < 128){
    float p = fmaxf(mv<128,32>(W2p, (const uint4*)s_p1, tid) + b2[tid], 0.f);
    float pN = __shfl_down(p, 1);
    if (!(tid & 1)){
      unsigned* dst = (unsigned*)(out + (size_t)10240000 + ((size_t)b*200 + t)*512);
      dst[tid>>1] = pkh2(p, pN);
    }
  }
}

// Mel hoisted: decoder left packed dec_in at out_mel[b][t][0:128] u32.
__global__ __launch_bounds__(512) void mel_kernel(
    const float* __restrict__ bmel, const uint4* __restrict__ Wmelp,
    float* __restrict__ out)
{
  int t = blockIdx.x, b = blockIdx.y;
  int tid = threadIdx.x;
  __shared__ __align__(16) unsigned s_d[128];
  float* po = out + ((size_t)b*200 + t)*400;
  if (tid < 128) s_d[tid] = ((const unsigned*)po)[tid];
  __syncthreads();
  if (tid < 400){
    float r = mvc<400,32,8>(Wmelp, (const uint4*)s_d, tid) + bmel[tid];
    __builtin_nontemporal_store(r, &po[tid]);
  }
}

// ---------------- decoder (13 barriers/step; R14 + P5 d-half fix) ----------
// Merges vs R11 (math-identical): P4+QT via in-wave splitK4, P7+DM via
// in-wave splitK4, softmax-final folded into P6 (e-weighted stream x 1/S)
// + align-store in CR idle threads, G2 moved into next step's P1 (epilogue
// handles t=199). R14 BUG fixed here: P5 must PARTITION d by dh (tp offset
// dh*16*512 uint4, 16 groups per half) — R14 summed the full d-range twice.
__global__ __launch_bounds__(1024, 1) void decoder(
   const float* __restrict__ biha, const float* __restrict__ bhha,
   const float* __restrict__ vvec, const float* __restrict__ bp,
   const float* __restrict__ bd1i, const float* __restrict__ bd1h,
   const float* __restrict__ bd2i, const float* __restrict__ bd2h,
   const uint4* __restrict__ Wihap, const uint4* __restrict__ Whhap,
   const uint4* __restrict__ Wqp, const uint4* __restrict__ Wpp,
   const uint4* __restrict__ Wd1ip, const uint4* __restrict__ Wd1hp,
   const uint4* __restrict__ Wd2ip, const uint4* __restrict__ Wd2hp,
   const unsigned* __restrict__ tpm, const unsigned* __restrict__ encH,
   float* __restrict__ out)
{
  const int tid = threadIdx.x;
  const int b = blockIdx.x;

  __shared__ __align__(16) unsigned s_cin2[192]; // [pre2(64) | ctx(128)]
  __shared__ __align__(16) unsigned s_cat2[256]; // [attn_h(128) | ctx(128)]
  __shared__ __align__(16) unsigned s_di2[128];
  __shared__ __align__(16) unsigned s_h12[128];
  __shared__ __align__(16) unsigned s_h22[128];
  __shared__ float  s_gha[768], s_gh1[768], s_gh2[768];
  __shared__ float  s_g[768];
  __shared__ float  s_ahf[256], s_h1f[256], s_h2f[256];
  __shared__ float  s_dif[256];
  __shared__ float4 s_tv[128];      // {tq[2d2], tq[2d2+1], v[2d2], v[2d2+1]}
  __shared__ float  s_lp[2][512];
  __shared__ float2 s_cp[8][128];
  __shared__ float  s_eexp[512];    // unnormalized exp(logit)
  __shared__ float  s_red[8];       // per-wave partial sums

  if (tid < 192) s_cin2[tid] = 0u;
  if (tid < 256){ s_cat2[tid]=0u; s_ahf[tid]=0.f; s_h1f[tid]=0.f; s_h2f[tid]=0.f; }
  if (tid < 128){ s_di2[tid]=0u; s_h12[tid]=0u; s_h22[tid]=0u;
                  s_tv[tid].z = vvec[2*tid]; s_tv[tid].w = vvec[2*tid+1]; }
  __syncthreads();

  const unsigned* encB = encH + (size_t)b*65536;
  const uint4*    tpm4 = (const uint4*)tpm + (size_t)b*16384;
  float* outMel = out + (size_t)b*80000;
  float* outAl  = out + 10240000ull + (size_t)b*102400;

  const uint4* cin4 = (const uint4*)s_cin2;
  const uint4* cat4 = (const uint4*)s_cat2;
  const uint4* di4  = (const uint4*)s_di2;
  const uint4* h14  = (const uint4*)s_h12;
  const uint4* h24  = (const uint4*)s_h22;

  for (int t = 0; t < 200; ++t){
    // ===== P1: gha[768] || G2 gates of step t-1 [256]
    if (tid < 768){
      s_gha[tid] = mvc<768,32,8>(Whhap, cat4, tid) + bhha[tid];
    } else if (t > 0){
      int i = tid - 768;
      float rr = s_g[i], z = s_g[256+i];
      float nv = tanhf2(s_g[512+i] + rr*s_gh2[512+i]);
      float h  = nv + z*(s_h2f[i] - nv);
      s_h2f[i] = h;
      float di = s_dif[i] + h;
      float hN = __shfl_down(h, 1), dN = __shfl_down(di, 1);
      if (!(i&1)){
        s_h22[i>>1] = pkh2(h, hN);
        ((unsigned*)(outMel + (size_t)(t-1)*400))[i>>1] = pkh2(di, dN);
      }
    }
    __syncthreads();                                        // bar 1
    // ===== P2: gh1[768] || gh2 rows 0..191 || pre2 load [64]
    if (tid < 768){
      s_gh1[tid] = mvc<768,32,8>(Wd1hp, h14, tid) + bd1h[tid];
    } else if (tid < 960){
      int r = tid - 768;
      s_gh2[r] = mvc<768,32,8>(Wd2hp, h24, r) + bd2h[r];
    } else {
      s_cin2[tid-960] = ((const unsigned*)(outAl + (size_t)t*512))[tid-960];
    }
    __syncthreads();                                        // bar 2
    // ===== P3: gi_a[768] (K8=48) || gh2 rows 192..383
    if (tid < 768){
      float gi = mvc<768,48,8>(Wihap, cin4, tid) + biha[tid];
      s_g[tid] = (tid < 512) ? sigm(gi + s_gha[tid]) : gi;
    } else if (tid < 960){
      int r = 192 + tid - 768;
      s_gh2[r] = mvc<768,32,8>(Wd2hp, h24, r) + bd2h[r];
    }
    __syncthreads();                                        // bar 3
    // ===== GA: attn-GRU gates [256] || gh2 rows 384..575
    if (tid < 256){
      float rr = s_g[tid], z = s_g[256+tid];
      float nv = tanhf2(s_g[512+tid] + rr*s_gha[512+tid]);
      float h  = nv + z*(s_ahf[tid] - nv);
      s_ahf[tid] = h;
      float hN = __shfl_down(h, 1);
      if (!(tid&1)) s_cat2[tid>>1] = pkh2(h, hN);
    } else if (tid < 448){
      int r = 384 + tid - 256;
      s_gh2[r] = mvc<768,32,8>(Wd2hp, h24, r) + bd2h[r];
    }
    __syncthreads();                                        // bar 4
    // ===== P4Q: q = Wq@attn_h, in-wave splitK4 + tanh (1024, 1 round)
    {
      int row = tid >> 2, kp = tid & 3;
      float p = mvc<256,8,8>(Wqp + (size_t)(kp*8)*256, cat4 + kp*8, row);
      p += __shfl_xor(p, 1);
      p += __shfl_xor(p, 2);
      if (!(tid & 3)){
        float tq = tanhf2(p);
        ((float*)&s_tv[row>>1])[row&1] = tq;
      }
    }
    __syncthreads();                                        // bar 5
    // ===== P5: logits via tanh-sum identity; dh PARTITIONS d (16 groups each)
    {
      int tt = tid & 511, dh = tid >> 9;
      const uint4* tp = tpm4 + tt + (size_t)(dh*16)*512;
      float acc = 0.f;
      #pragma unroll 1
      for (int g = 0; g < 16; g += 8){
        uint4 T[8];
        #pragma unroll
        for (int i = 0; i < 8; ++i) T[i] = tp[(size_t)(g+i)*512];
        #pragma unroll
        for (int i = 0; i < 8; ++i){
          #pragma unroll
          for (int j = 0; j < 4; ++j){
            unsigned u = ((const unsigned*)&T[i])[j];
            h2f ta = __builtin_bit_cast(h2f, u);
            float4 tv = s_tv[(dh*16 + g + i)*4 + j];
            float ta0 = (float)ta.x, ta1 = (float)ta.y;
            float n0 = ta0 + tv.x, n1 = ta1 + tv.y;
            float d0 = fmaf(ta0, tv.x, 1.f), d1 = fmaf(ta1, tv.y, 1.f);
            float r  = frcp(d0*d1);
            acc = fmaf(fmaf(tv.w*n1, d0, (tv.z*n0)*d1), r, acc);
          }
        }
      }
      s_lp[dh][tt] = acc;
    }
    __syncthreads();                                        // bar 6
    // ===== SM: e = exp(logit) (unnormalized) + per-wave sums
    if (tid < 512){
      float lg = s_lp[0][tid] + s_lp[1][tid];
      float e = fexp2(LOG2E*lg);
      s_eexp[tid] = e;
      float s = e;
      #pragma unroll
      for (int off = 32; off >= 1; off >>= 1) s += __shfl_xor(s, off);
      if ((tid & 63) == 0) s_red[tid>>6] = s;
    }
    __syncthreads();                                        // bar 7
    // ===== P6: ctx partials, e-weighted, x(1/S) at end (1024)
    {
      float S = ((s_red[0]+s_red[1])+(s_red[2]+s_red[3]))
              + ((s_red[4]+s_red[5])+(s_red[6]+s_red[7]));
      float rS = frcp(S);
      int d2 = tid & 127, tc = tid >> 7;
      const unsigned* eb = encB + d2 + (size_t)tc*8192;
      float ax = 0.f, ay = 0.f;
      #pragma unroll 1
      for (int c = 0; c < 64; c += 16){
        unsigned ew[16];
        #pragma unroll
        for (int i = 0; i < 16; ++i) ew[i] = eb[(size_t)(c+i)*128];
        #pragma unroll
        for (int i = 0; i < 16; ++i){
          float a = s_eexp[tc*64 + c + i];
          h2f e2 = __builtin_bit_cast(h2f, ew[i]);
          ax += a*(float)e2.x; ay += a*(float)e2.y;
        }
      }
      s_cp[tc][d2] = make_float2(ax*rS, ay*rS);
    }
    __syncthreads();                                        // bar 8
    // ===== CR: ctx reduce + pack [256] || align store [tid 512..1023]
    if (tid < 256){
      const float* cp = (const float*)s_cp;
      float c = 0.f;
      #pragma unroll
      for (int k = 0; k < 8; ++k) c += cp[k*256 + tid];
      float cN = __shfl_down(c, 1);
      if (!(tid&1)){ unsigned pk = pkh2(c, cN); s_cin2[64+(tid>>1)] = pk; s_cat2[128+(tid>>1)] = pk; }
    } else if (tid >= 512){
      int tt = tid - 512;
      float S = ((s_red[0]+s_red[1])+(s_red[2]+s_red[3]))
              + ((s_red[4]+s_red[5])+(s_red[6]+s_red[7]));
      float a = s_eexp[tt] * frcp(S);
      __builtin_nontemporal_store(a, &outAl[(size_t)t*512 + tt]);
    }
    __syncthreads();                                        // bar 9
    // ===== P7D: dec_in = Wp@cat(attn_h,ctx), in-wave splitK4 + bp + pack
    {
      int row = tid >> 2, kp = tid & 3;
      float p = mvc<256,16,8>(Wpp + (size_t)(kp*16)*256, cat4 + kp*16, row);
      p += __shfl_xor(p, 1);
      p += __shfl_xor(p, 2);
      if (!(tid & 3)){
        float di = p + bp[row];
        s_dif[row] = di;
        float dN = __shfl_down(di, 4);
        if (!(tid & 7)) s_di2[row>>1] = pkh2(di, dN);
      }
    }
    __syncthreads();                                        // bar 10
    // ===== P8: gi_d1 [768] || gh2 rows 576..671
    if (tid < 768){
      float gi = mvc<768,32,8>(Wd1ip, di4, tid) + bd1i[tid];
      s_g[tid] = (tid < 512) ? sigm(gi + s_gh1[tid]) : gi;
    } else if (tid < 864){
      int r = 576 + tid - 768;
      s_gh2[r] = mvc<768,32,8>(Wd2hp, h24, r) + bd2h[r];
    }
    __syncthreads();                                        // bar 11
    // ===== G1: gates h1 + residual [256]
    if (tid < 256){
      float rr = s_g[tid], z = s_g[256+tid];
      float nv = tanhf2(s_g[512+tid] + rr*s_gh1[512+tid]);
      float h  = nv + z*(s_h1f[tid] - nv);
      s_h1f[tid] = h;
      float di = s_dif[tid] + h; s_dif[tid] = di;
      float hN = __shfl_down(h, 1), dN = __shfl_down(di, 1);
      if (!(tid&1)){ s_h12[tid>>1] = pkh2(h, hN); s_di2[tid>>1] = pkh2(di, dN); }
    }
    __syncthreads();                                        // bar 12
    // ===== P9: gi_d2 [768] || gh2 rows 672..767  (G2 runs in next P1)
    if (tid < 768){
      float gi = mvc<768,32,8>(Wd2ip, di4, tid) + bd2i[tid];
      s_g[tid] = (tid < 512) ? sigm(gi + s_gh2[tid]) : gi;
    } else if (tid < 864){
      int r = 672 + tid - 768;
      s_gh2[r] = mvc<768,32,8>(Wd2hp, h24, r) + bd2h[r];
    }
    __syncthreads();                                        // bar 13
  }
  // ===== epilogue: G2 for t=199 (mel stash only; state updates unneeded)
  if (tid < 256){
    int i = tid;
    float rr = s_g[i], z = s_g[256+i];
    float nv = tanhf2(s_g[512+i] + rr*s_gh2[512+i]);
    float h  = nv + z*(s_h2f[i] - nv);
    float di = s_dif[i] + h;
    float dN = __shfl_down(di, 1);
    if (!(i&1)) ((unsigned*)(outMel + (size_t)199*400))[i>>1] = pkh2(di, dN);
  }
}

// ---------------- launch ----------------
extern "C" void kernel_launch(void* const* d_in, const int* in_sizes, int n_in,
                              void* d_out, int out_size, void* d_ws, size_t ws_size,
                              hipStream_t stream){
  (void)in_sizes; (void)n_in; (void)out_size; (void)ws_size;
  const float* enc    = (const float*)d_in[0];
  const float* inputs = (const float*)d_in[1];
  const float* W1 = (const float*)d_in[2];   const float* b1 = (const float*)d_in[3];
  const float* W2 = (const float*)d_in[4];   const float* b2 = (const float*)d_in[5];
  const float* Wiha = (const float*)d_in[6]; const float* Whha = (const float*)d_in[7];
  const float* biha = (const float*)d_in[8]; const float* bhha = (const float*)d_in[9];
  const float* Wq = (const float*)d_in[10];  const float* v  = (const float*)d_in[11];
  const float* Wm = (const float*)d_in[12];
  const float* Wp = (const float*)d_in[13];  const float* bp = (const float*)d_in[14];
  const float* Wd1i = (const float*)d_in[15]; const float* Wd1h = (const float*)d_in[16];
  const float* bd1i = (const float*)d_in[17]; const float* bd1h = (const float*)d_in[18];
  const float* Wd2i = (const float*)d_in[19]; const float* Wd2h = (const float*)d_in[20];
  const float* bd2i = (const float*)d_in[21]; const float* bd2h = (const float*)d_in[22];
  const float* Wmel = (const float*)d_in[23]; const float* bmel = (const float*)d_in[24];

  char* ws = (char*)d_ws;
  uint4* W1p   = (uint4*)(ws + OFF_W1);
  uint4* W2p   = (uint4*)(ws + OFF_W2);
  uint4* Wihap = (uint4*)(ws + OFF_WIHA);
  uint4* Whhap = (uint4*)(ws + OFF_WHHA);
  uint4* Wqp   = (uint4*)(ws + OFF_WQ);
  uint4* Wpp   = (uint4*)(ws + OFF_WP);
  uint4* Wd1ip = (uint4*)(ws + OFF_WD1I);
  uint4* Wd1hp = (uint4*)(ws + OFF_WD1H);
  uint4* Wd2ip = (uint4*)(ws + OFF_WD2I);
  uint4* Wd2hp = (uint4*)(ws + OFF_WD2H);
  uint4* Wmelp = (uint4*)(ws + OFF_WMEL);
  uint4* Wmp   = (uint4*)(ws + OFF_WM);
  unsigned* tpm  = (unsigned*)(ws + OFF_TPM);
  unsigned* encH = (unsigned*)(ws + OFF_ENCH);

  auto P = [&](const float* s, uint4* dst, int N, int K){
    int k8 = K/8, tot = N*k8;
    pack_w<<<(tot+255)/256, 256, 0, stream>>>(s, dst, N, k8);
  };
  P(W1, W1p, 256, 400);   P(W2, W2p, 128, 256);
  P(Wiha, Wihap, 768, 384); P(Whha, Whhap, 768, 256);
  P(Wq, Wqp, 256, 256);   P(Wm, Wmp, 256, 256);
  P(Wp, Wpp, 256, 512);
  P(Wd1i, Wd1ip, 768, 256); P(Wd1h, Wd1hp, 768, 256);
  P(Wd2i, Wd2ip, 768, 256); P(Wd2h, Wd2hp, 768, 256);
  P(Wmel, Wmelp, 400, 256);

  conv_enc<<<32768, 256, 0, stream>>>(enc, encH);
  pm_kernel<<<dim3(128,128), 1024, 0, stream>>>(enc, Wmp, tpm);
  prenet_kernel<<<dim3(200,128), 256, 0, stream>>>(inputs, b1, b2, W1p, W2p, (float*)d_out);

  decoder<<<128, 1024, 0, stream>>>(
      biha, bhha, v, bp, bd1i, bd1h, bd2i, bd2h,
      Wihap, Whhap, Wqp, Wpp, Wd1ip, Wd1hp, Wd2ip, Wd2hp,
      tpm, encH, (float*)d_out);

  mel_kernel<<<dim3(200,128), 512, 0, stream>>>(bmel, Wmelp, (float*)d_out);
}